// Round 17
// baseline (418.904 us; speedup 1.0000x reference)
//
#include <hip/hip_runtime.h>

typedef unsigned short u16;
typedef unsigned int   u32;

#define NB     512
#define NHEADS 8
#define HW     361
#define NPIX   184832      /* NB*HW */
#define NTOT   768
#define EPSBN  1e-5f
#define RS     0.17677669529663687f   /* sqrt(32)/32 */

typedef __bf16 bf16x8 __attribute__((ext_vector_type(8)));
typedef float  f32x4  __attribute__((ext_vector_type(4)));

__device__ __forceinline__ u16 f2bf(float f) {
  u32 u = __float_as_uint(f);
  u += 0x7fffu + ((u >> 16) & 1u);          // round-to-nearest-even
  return (u16)(u >> 16);
}
__device__ __forceinline__ float bf2f(u16 v) {
  return __uint_as_float(((u32)v) << 16);
}
__device__ __forceinline__ bf16x8 ldb8(const void* p) {
  return __builtin_bit_cast(bf16x8, *(const uint4*)p);
}
__device__ __forceinline__ float dot2(u32 a, u32 b) {
  return bf2f((u16)a) * bf2f((u16)b) + bf2f((u16)(a >> 16)) * bf2f((u16)(b >> 16));
}
__device__ __forceinline__ float dot8(uint4 a, uint4 b) {
  return dot2(a.x, b.x) + dot2(a.y, b.y) + dot2(a.z, b.z) + dot2(a.w, b.w);
}

// ---------------- kernel 0: W -> bf16 [768][256]; bias; zero sx
__global__ __launch_bounds__(256) void k_prep(
    const float* __restrict__ Wq, const float* __restrict__ bq,
    const float* __restrict__ Wk, const float* __restrict__ bk,
    const float* __restrict__ Wv, const float* __restrict__ bv,
    u16* __restrict__ Wall, float* __restrict__ ball,
    float* __restrict__ sx) {
  const int n = blockIdx.x, t = threadIdx.x;
  const float* src; const float* bs; int r;
  if (n < 256)      { src = Wq; bs = bq; r = n; }
  else if (n < 512) { src = Wk; bs = bk; r = n - 256; }
  else              { src = Wv; bs = bv; r = n - 512; }
  Wall[n * 256 + t] = f2bf(src[r * 256 + t]);
  if (t == 0) ball[n] = bs[r];
  if (n == 0) sx[t] = 0.f;
}

// ---------------- kernel 1: M partials + sx + fused xT write (x read ONCE)
__global__ __launch_bounds__(512) void k_M(
    const float* __restrict__ x, u16* __restrict__ xT,
    float* __restrict__ Mpart, float* __restrict__ sx) {
  __shared__ u16 Als[256 * 64];                    // 32 KB
  const int tid = threadIdx.x, g = blockIdx.x;     // images 2g, 2g+1
  const int lane = tid & 63, w = tid >> 6;         // 8 waves
  const int l15 = lane & 15, kq = lane >> 4;
  const int sc  = tid >> 4;
  const int sq  = tid & 15;
  const int wpx = tid & 63;
  const int wcs = tid >> 6;
  char* Ab = (char*)Als;

  float sxp[8];
  f32x4 acc[2][16];
  #pragma unroll
  for (int i = 0; i < 8; ++i) sxp[i] = 0.f;
  #pragma unroll
  for (int f2 = 0; f2 < 16; ++f2) {
    acc[0][f2] = (f32x4){0.f, 0.f, 0.f, 0.f};
    acc[1][f2] = (f32x4){0.f, 0.f, 0.f, 0.f};
  }

  #pragma unroll 1
  for (int ch = 0; ch < 12; ++ch) {
    const int img = (ch >= 6) ? 1 : 0;
    const int px0 = (ch - img * 6) * 64;
    const int bb  = g * 2 + img;
    const int pb  = px0 + sq * 4;
    #pragma unroll
    for (int i = 0; i < 8; ++i) {
      const int c = sc + 32 * i;
      const float* xp = x + ((size_t)bb * 256 + c) * HW + pb;
      float v0, v1, v2, v3;
      if (pb + 3 < HW) {
        const float4 f4 = *(const float4*)xp;
        v0 = f4.x; v1 = f4.y; v2 = f4.z; v3 = f4.w;
      } else {
        v0 = (pb + 0 < HW) ? xp[0] : 0.f;
        v1 = (pb + 1 < HW) ? xp[1] : 0.f;
        v2 = (pb + 2 < HW) ? xp[2] : 0.f;
        v3 = (pb + 3 < HW) ? xp[3] : 0.f;
      }
      sxp[i] += v0 + v1 + v2 + v3;
      const u32 lo = (u32)f2bf(v0) | ((u32)f2bf(v1) << 16);
      const u32 hi = (u32)f2bf(v2) | ((u32)f2bf(v3) << 16);
      const int slot = (sq >> 1) ^ (c & 7);
      *(uint2*)(Ab + c * 128 + slot * 16 + (sq & 1) * 8) = make_uint2(lo, hi);
    }
    __syncthreads();
    #pragma unroll
    for (int kk = 0; kk < 2; ++kk) {
      const int gl = kk * 4 + kq;
      const int so = ((gl ^ (l15 & 7)) << 4);
      const int r0 = w * 32 + l15;
      const bf16x8 a0 = ldb8(Ab + r0 * 128 + so);
      const bf16x8 a1 = ldb8(Ab + (r0 + 16) * 128 + so);
      #pragma unroll
      for (int f2 = 0; f2 < 16; ++f2) {
        const bf16x8 b = ldb8(Ab + (f2 * 16 + l15) * 128 + so);
        acc[0][f2] = __builtin_amdgcn_mfma_f32_16x16x32_bf16(a0, b, acc[0][f2], 0, 0, 0);
        acc[1][f2] = __builtin_amdgcn_mfma_f32_16x16x32_bf16(a1, b, acc[1][f2], 0, 0, 0);
      }
    }
    const int pxg = px0 + wpx;
    if (pxg < HW) {
      __align__(16) u16 tmp[32];
      #pragma unroll
      for (int j = 0; j < 32; ++j) {
        const int c = wcs * 32 + j;
        tmp[j] = Als[c * 64 + (((wpx >> 3) ^ (c & 7)) << 3) + (wpx & 7)];
      }
      uint4* dst = (uint4*)(xT + ((size_t)bb * HW + pxg) * 256 + wcs * 32);
      dst[0] = ((const uint4*)tmp)[0];
      dst[1] = ((const uint4*)tmp)[1];
      dst[2] = ((const uint4*)tmp)[2];
      dst[3] = ((const uint4*)tmp)[3];
    }
    __syncthreads();
  }
  float* mp = Mpart + (size_t)g * 65536;
  #pragma unroll
  for (int f1 = 0; f1 < 2; ++f1)
    #pragma unroll
    for (int f2 = 0; f2 < 16; ++f2)
      #pragma unroll
      for (int j = 0; j < 4; ++j) {
        const int c1 = w * 32 + f1 * 16 + kq * 4 + j;
        const int c2 = f2 * 16 + l15;
        mp[c1 * 256 + c2] = acc[f1][f2][j];
      }
  #pragma unroll
  for (int i = 0; i < 8; ++i) {
    float v = sxp[i];
    v += __shfl_down(v, 8); v += __shfl_down(v, 4);
    v += __shfl_down(v, 2); v += __shfl_down(v, 1);
    if (sq == 0) atomicAdd(&sx[sc + 32 * i], v);
  }
}

// ---------------- kernel 1c: reduce 256 partials -> Mg (deterministic)
__global__ __launch_bounds__(256) void k_red(const float* __restrict__ Mpart,
                                             float* __restrict__ Mg) {
  const int i = blockIdx.x * 256 + threadIdx.x;
  float s = 0.f;
  #pragma unroll 8
  for (int sl = 0; sl < 256; ++sl) s += Mpart[(size_t)sl * 65536 + i];
  Mg[i] = s;
}

// ---------------- kernel 2: finalize BN via moments: s_all, t_all
__global__ __launch_bounds__(256) void k_stats2(
    const float* __restrict__ Mg, const float* __restrict__ sx,
    const float* __restrict__ Wq, const float* __restrict__ bq,
    const float* __restrict__ Wk, const float* __restrict__ bk,
    const float* __restrict__ Wv, const float* __restrict__ bv,
    const float* __restrict__ gQ, const float* __restrict__ betaQ,
    const float* __restrict__ gK, const float* __restrict__ betaK,
    const float* __restrict__ gV, const float* __restrict__ betaV,
    float* __restrict__ s_all, float* __restrict__ t_all) {
  __shared__ float ws[256];
  __shared__ float r1[4], r2[4];
  const int n = blockIdx.x, i = threadIdx.x;
  const int which = n >> 8, r = n & 255;
  const float* src = (which == 0) ? Wq : (which == 1) ? Wk : Wv;
  const float wi = src[r * 256 + i];
  ws[i] = wi;
  __syncthreads();
  float colsum = 0.f;
  #pragma unroll 4
  for (int j = 0; j < 256; ++j) colsum += Mg[j * 256 + i] * ws[j];
  float p1 = wi * sx[i];
  float p2 = wi * colsum;
  p1 += __shfl_down(p1, 32); p2 += __shfl_down(p2, 32);
  p1 += __shfl_down(p1, 16); p2 += __shfl_down(p2, 16);
  p1 += __shfl_down(p1, 8);  p2 += __shfl_down(p2, 8);
  p1 += __shfl_down(p1, 4);  p2 += __shfl_down(p2, 4);
  p1 += __shfl_down(p1, 2);  p2 += __shfl_down(p2, 2);
  p1 += __shfl_down(p1, 1);  p2 += __shfl_down(p2, 1);
  const int wv = i >> 6;
  if ((i & 63) == 0) { r1[wv] = p1; r2[wv] = p2; }
  __syncthreads();
  if (i == 0) {
    const float S1 = r1[0] + r1[1] + r1[2] + r1[3];
    const float S2 = r2[0] + r2[1] + r2[2] + r2[3];
    const float* bs = (which == 0) ? bq : (which == 1) ? bk : bv;
    const float* gs = (which == 0) ? gQ : (which == 1) ? gK : gV;
    const float* be = (which == 0) ? betaQ : (which == 1) ? betaK : betaV;
    const float b = bs[r];
    const float P = (float)NPIX;
    const float mean = (S1 + P * b) / P;
    const float Ey2  = (S2 + 2.f * b * S1 + P * b * b) / P;
    const float var  = Ey2 - mean * mean;
    const float s    = gs[r] * rsqrtf(var + EPSBN);
    s_all[n] = s;
    t_all[n] = be[r] - s * mean;
  }
}

// ---------------- kernel 3a: QK-GEMM + softmax -> aL4 (78 KB LDS, 2 blocks/CU)
__global__ __launch_bounds__(768) void k_qk(
    const u16* __restrict__ xT, const u16* __restrict__ Wall,
    const float* __restrict__ ball,
    const float* __restrict__ s_all, const float* __restrict__ t_all,
    float* __restrict__ aL4) {
  __shared__ u16 Wqk[64 * 256];                    // 32 KB, XOR-swz rows
  __shared__ __align__(16) u16 Pq[HW * 64];        // 46.2 KB, 128B rows, granule swz
  __shared__ float stl[2 * 64];
  const int tid = threadIdx.x, wg = blockIdx.x;
  const int xcd = wg & 7, rest = wg >> 3;
  const int h = rest & 7, bb = xcd + 8 * (rest >> 3);
  const char* Pb = (const char*)Pq;

  if (tid < 64) {
    const int which = tid >> 5, c32 = tid & 31;
    const int n = which * 256 + h * 32 + c32;
    float s = s_all[n];
    float t = s * ball[n] + t_all[n];
    if (which == 0) { s *= RS; t *= RS; }
    stl[tid] = s; stl[64 + tid] = t;
  }
  #pragma unroll
  for (int i = 0; i < 3; ++i) {
    const int gi = tid + i * 768;
    if (gi < 2048) {
      const int lr = gi >> 5, gg = gi & 31;
      const int n = ((lr < 32) ? 0 : 256) + h * 32 + (lr & 31);
      uint4 v = *(const uint4*)(Wall + (size_t)n * 256 + gg * 8);
      *(uint4*)((char*)Wqk + lr * 512 + (gg ^ (lr & 7)) * 16) = v;
    }
  }
  __syncthreads();

  const int lane = tid & 63, wv = tid >> 6;
  const int l15 = lane & 15, kq = lane >> 4;
  const u16* xTb = xT + (size_t)bb * HW * 256;

  f32x4 acc[4][2];
  #pragma unroll
  for (int f = 0; f < 4; ++f) {
    acc[f][0] = (f32x4){0.f, 0.f, 0.f, 0.f};
    acc[f][1] = (f32x4){0.f, 0.f, 0.f, 0.f};
  }
  #pragma unroll
  for (int kb = 0; kb < 4; ++kb) {                 // serial batches of 4 uint4
    uint4 bfr[4];
    #pragma unroll
    for (int j = 0; j < 2; ++j) {
      const int ks = kb * 2 + j;
      bfr[j * 2]     = *(const uint4*)(xTb + (size_t)(wv * 32      + l15) * 256 + ks * 32 + kq * 8);
      bfr[j * 2 + 1] = *(const uint4*)(xTb + (size_t)(wv * 32 + 16 + l15) * 256 + ks * 32 + kq * 8);
    }
    #pragma unroll
    for (int j = 0; j < 2; ++j) {
      const int ks = kb * 2 + j;
      const bf16x8 b0 = __builtin_bit_cast(bf16x8, bfr[j * 2]);
      const bf16x8 b1 = __builtin_bit_cast(bf16x8, bfr[j * 2 + 1]);
      const int slot = ((ks * 4 + kq) ^ (l15 & 7)) * 16;
      #pragma unroll
      for (int f = 0; f < 4; ++f) {
        const bf16x8 a = ldb8((const char*)Wqk + (f * 16 + l15) * 512 + slot);
        acc[f][0] = __builtin_amdgcn_mfma_f32_16x16x32_bf16(a, b0, acc[f][0], 0, 0, 0);
        acc[f][1] = __builtin_amdgcn_mfma_f32_16x16x32_bf16(a, b1, acc[f][1], 0, 0, 0);
      }
    }
  }
  // epilogue -> Pq [px][64ch], granule (2f + kq/2) ^ (px&7)
  #pragma unroll
  for (int f = 0; f < 4; ++f) {
    const int ch0 = f * 16 + kq * 4;
    const float s0 = stl[ch0],     t0 = stl[64 + ch0];
    const float s1 = stl[ch0 + 1], t1 = stl[64 + ch0 + 1];
    const float s2 = stl[ch0 + 2], t2 = stl[64 + ch0 + 2];
    const float s3 = stl[ch0 + 3], t3 = stl[64 + ch0 + 3];
    #pragma unroll
    for (int p2 = 0; p2 < 2; ++p2) {
      const int px = wv * 32 + p2 * 16 + l15;
      if (px < HW) {
        const u32 lo = (u32)f2bf(s0 * acc[f][p2][0] + t0)
                     | ((u32)f2bf(s1 * acc[f][p2][1] + t1) << 16);
        const u32 hi = (u32)f2bf(s2 * acc[f][p2][2] + t2)
                     | ((u32)f2bf(s3 * acc[f][p2][3] + t3) << 16);
        const int slot = (2 * f + (kq >> 1)) ^ (px & 7);
        *(uint2*)((char*)Pq + px * 128 + slot * 16 + (kq & 1) * 8) = make_uint2(lo, hi);
      }
    }
  }
  __syncthreads();

  if (tid < HW) {
    const int px = tid;
    const int yy = px / 19, xx = px - yy * 19;
    const bool i0 = yy > 0, i1 = yy < 18, i2 = xx > 0, i3 = xx < 18;
    const int pn0 = i0 ? px - 19 : px, pn1 = i1 ? px + 19 : px;
    const int pn2 = i2 ? px - 1  : px, pn3 = i3 ? px + 1  : px;
    uint4 q[4], k0[4], k1[4], k2[4], k3[4];
    #pragma unroll
    for (int g = 0; g < 4; ++g) {
      q[g]  = *(const uint4*)(Pb + px  * 128 + ((g ^ (px  & 7)) * 16));
      k0[g] = *(const uint4*)(Pb + pn0 * 128 + (((4 + g) ^ (pn0 & 7)) * 16));
      k1[g] = *(const uint4*)(Pb + pn1 * 128 + (((4 + g) ^ (pn1 & 7)) * 16));
      k2[g] = *(const uint4*)(Pb + pn2 * 128 + (((4 + g) ^ (pn2 & 7)) * 16));
      k3[g] = *(const uint4*)(Pb + pn3 * 128 + (((4 + g) ^ (pn3 & 7)) * 16));
    }
    float l0 = 0.f, l1 = 0.f, l2 = 0.f, l3 = 0.f;
    #pragma unroll
    for (int g = 0; g < 4; ++g) {
      l0 += dot8(q[g], k0[g]); l1 += dot8(q[g], k1[g]);
      l2 += dot8(q[g], k2[g]); l3 += dot8(q[g], k3[g]);
    }
    l0 = i0 ? l0 : 0.f; l1 = i1 ? l1 : 0.f;
    l2 = i2 ? l2 : 0.f; l3 = i3 ? l3 : 0.f;
    const float mx = fmaxf(fmaxf(l0, l1), fmaxf(l2, l3));
    const float e0 = __expf(l0 - mx), e1 = __expf(l1 - mx);
    const float e2 = __expf(l2 - mx), e3 = __expf(l3 - mx);
    const float inv = 1.f / (e0 + e1 + e2 + e3);
    float4 av;
    av.x = i0 ? e0 * inv : 0.f;
    av.y = i1 ? e1 * inv : 0.f;
    av.z = i2 ? e2 * inv : 0.f;
    av.w = i3 ? e3 * inv : 0.f;
    *(float4*)&aL4[(((size_t)(bb * NHEADS + h) * HW) + px) * 4] = av;
  }
}

// ---------------- kernel 3b: V-GEMM + weighted sum + ReLU + residual (45 KB LDS)
__global__ __launch_bounds__(768) void k_v(
    const u16* __restrict__ xT, const u16* __restrict__ Wall,
    const float* __restrict__ ball,
    const float* __restrict__ s_all, const float* __restrict__ t_all,
    const float* __restrict__ aL4, const float* __restrict__ x,
    float* __restrict__ out) {
  __shared__ u16 Wv[32 * 256];                     // 16 KB, XOR-swz rows
  __shared__ __align__(16) u16 Pv[HW * 40];        // 28.9 KB, 80B rows (5x16B)
  __shared__ float stl[2 * 32];
  const int tid = threadIdx.x, wg = blockIdx.x;
  const int xcd = wg & 7, rest = wg >> 3;
  const int h = rest & 7, bb = xcd + 8 * (rest >> 3);
  const char* Pb = (const char*)Pv;

  const bool pact = tid < 2 * HW;
  const int  ppx  = pact ? ((tid < HW) ? tid : tid - HW) : 0;
  const int  poc0 = (tid < HW) ? 0 : 16;
  const size_t pgb = ((size_t)bb * 256 + h * 32 + poc0) * HW + ppx;
  float xres[16];
  float4 aw = make_float4(0.f, 0.f, 0.f, 0.f);
  if (pact) {
    aw = *(const float4*)&aL4[(((size_t)(bb * NHEADS + h) * HW) + ppx) * 4];
    #pragma unroll
    for (int o = 0; o < 16; ++o) xres[o] = x[pgb + (size_t)o * HW];
  }

  if (tid < 32) {
    const int n = 512 + h * 32 + tid;
    const float s = s_all[n];
    stl[tid] = s; stl[32 + tid] = s * ball[n] + t_all[n];
  }
  #pragma unroll
  for (int i = 0; i < 2; ++i) {
    const int gi = tid + i * 768;
    if (gi < 1024) {
      const int lr = gi >> 5, gg = gi & 31;
      const int n = 512 + h * 32 + lr;
      uint4 v = *(const uint4*)(Wall + (size_t)n * 256 + gg * 8);
      *(uint4*)((char*)Wv + lr * 512 + (gg ^ (lr & 7)) * 16) = v;
    }
  }
  __syncthreads();

  const int lane = tid & 63, wv = tid >> 6;
  const int l15 = lane & 15, kq = lane >> 4;
  const u16* xTb = xT + (size_t)bb * HW * 256;

  f32x4 acc[2][2];
  acc[0][0] = (f32x4){0.f,0.f,0.f,0.f}; acc[0][1] = (f32x4){0.f,0.f,0.f,0.f};
  acc[1][0] = (f32x4){0.f,0.f,0.f,0.f}; acc[1][1] = (f32x4){0.f,0.f,0.f,0.f};
  #pragma unroll
  for (int kb = 0; kb < 4; ++kb) {
    uint4 bfr[4];
    #pragma unroll
    for (int j = 0; j < 2; ++j) {
      const int ks = kb * 2 + j;
      bfr[j * 2]     = *(const uint4*)(xTb + (size_t)(wv * 32      + l15) * 256 + ks * 32 + kq * 8);
      bfr[j * 2 + 1] = *(const uint4*)(xTb + (size_t)(wv * 32 + 16 + l15) * 256 + ks * 32 + kq * 8);
    }
    #pragma unroll
    for (int j = 0; j < 2; ++j) {
      const int ks = kb * 2 + j;
      const bf16x8 b0 = __builtin_bit_cast(bf16x8, bfr[j * 2]);
      const bf16x8 b1 = __builtin_bit_cast(bf16x8, bfr[j * 2 + 1]);
      const int slot = ((ks * 4 + kq) ^ (l15 & 7)) * 16;
      #pragma unroll
      for (int f = 0; f < 2; ++f) {
        const bf16x8 a = ldb8((const char*)Wv + (f * 16 + l15) * 512 + slot);
        acc[f][0] = __builtin_amdgcn_mfma_f32_16x16x32_bf16(a, b0, acc[f][0], 0, 0, 0);
        acc[f][1] = __builtin_amdgcn_mfma_f32_16x16x32_bf16(a, b1, acc[f][1], 0, 0, 0);
      }
    }
  }
  // epilogue -> Pv [px][32ch], 80B rows (granule 0..3, natural spread)
  #pragma unroll
  for (int f = 0; f < 2; ++f) {
    const int ch0 = f * 16 + kq * 4;
    const float s0 = stl[ch0],     t0 = stl[32 + ch0];
    const float s1 = stl[ch0 + 1], t1 = stl[32 + ch0 + 1];
    const float s2 = stl[ch0 + 2], t2 = stl[32 + ch0 + 2];
    const float s3 = stl[ch0 + 3], t3 = stl[32 + ch0 + 3];
    #pragma unroll
    for (int p2 = 0; p2 < 2; ++p2) {
      const int px = wv * 32 + p2 * 16 + l15;
      if (px < HW) {
        const u32 lo = (u32)f2bf(s0 * acc[f][p2][0] + t0)
                     | ((u32)f2bf(s1 * acc[f][p2][1] + t1) << 16);
        const u32 hi = (u32)f2bf(s2 * acc[f][p2][2] + t2)
                     | ((u32)f2bf(s3 * acc[f][p2][3] + t3) << 16);
        *(uint2*)((char*)Pv + px * 80 + (2 * f + (kq >> 1)) * 16 + (kq & 1) * 8)
            = make_uint2(lo, hi);
      }
    }
  }
  __syncthreads();

  if (pact) {
    const int px = ppx;
    const int yy = px / 19, xx = px - yy * 19;
    const int pn0 = (yy > 0)  ? px - 19 : px, pn1 = (yy < 18) ? px + 19 : px;
    const int pn2 = (xx > 0)  ? px - 1  : px, pn3 = (xx < 18) ? px + 1  : px;
    const float a0 = aw.x, a1 = aw.y, a2 = aw.z, a3 = aw.w;
    const int gb = (poc0 >> 3) * 16;               // byte offset of oc half
    #pragma unroll
    for (int half = 0; half < 2; ++half) {
      const uint4 w0 = *(const uint4*)(Pb + pn0 * 80 + gb + half * 16);
      const uint4 w1 = *(const uint4*)(Pb + pn1 * 80 + gb + half * 16);
      const uint4 w2 = *(const uint4*)(Pb + pn2 * 80 + gb + half * 16);
      const uint4 w3 = *(const uint4*)(Pb + pn3 * 80 + gb + half * 16);
      const u32 u0[4] = {w0.x, w0.y, w0.z, w0.w};
      const u32 u1[4] = {w1.x, w1.y, w1.z, w1.w};
      const u32 u2[4] = {w2.x, w2.y, w2.z, w2.w};
      const u32 u3[4] = {w3.x, w3.y, w3.z, w3.w};
      #pragma unroll
      for (int p = 0; p < 4; ++p) {
        const int o = half * 8 + p * 2;
        float vlo = a0 * bf2f((u16)u0[p]) + a1 * bf2f((u16)u1[p])
                  + a2 * bf2f((u16)u2[p]) + a3 * bf2f((u16)u3[p]);
        float vhi = a0 * bf2f((u16)(u0[p] >> 16)) + a1 * bf2f((u16)(u1[p] >> 16))
                  + a2 * bf2f((u16)(u2[p] >> 16)) + a3 * bf2f((u16)(u3[p] >> 16));
        vlo = fmaxf(vlo, 0.f);
        vhi = fmaxf(vhi, 0.f);
        out[pgb + (size_t)o * HW]       = vlo + xres[o];
        out[pgb + (size_t)(o + 1) * HW] = vhi + xres[o + 1];
      }
    }
  }
}

// ---------------- workspace layout
constexpr size_t OFF_XT    = 0;
constexpr size_t SZ_XT     = (size_t)NPIX * 512 + 16384;
constexpr size_t OFF_WALL  = OFF_XT + SZ_XT;
constexpr size_t SZ_WALL   = (size_t)NTOT * 512;
constexpr size_t OFF_BALL  = OFF_WALL + SZ_WALL;
constexpr size_t OFF_M     = OFF_BALL + NTOT * 4;
constexpr size_t SZ_M      = 256 * 256 * 4;
constexpr size_t OFF_SX    = OFF_M + SZ_M;
constexpr size_t OFF_SALL  = OFF_SX + 256 * 4;
constexpr size_t OFF_TALL  = OFF_SALL + NTOT * 4;
constexpr size_t OFF_AL4   = OFF_TALL + NTOT * 4;
constexpr size_t SZ_AL4    = (size_t)NB * NHEADS * HW * 16;   // 23.7 MB
constexpr size_t OFF_MPART = OFF_AL4 + SZ_AL4;
constexpr size_t SZ_MPART  = (size_t)256 * 65536 * 4;         // 67 MB
constexpr size_t WS_NEEDED = OFF_MPART + SZ_MPART;

extern "C" void kernel_launch(void* const* d_in, const int* in_sizes, int n_in,
                              void* d_out, int out_size, void* d_ws, size_t ws_size,
                              hipStream_t stream) {
  (void)in_sizes; (void)n_in; (void)out_size;
  if (ws_size < WS_NEEDED) return;

  const float* x     = (const float*)d_in[0];
  const float* Wq    = (const float*)d_in[1];
  const float* bq    = (const float*)d_in[2];
  const float* Wk    = (const float*)d_in[3];
  const float* bk    = (const float*)d_in[4];
  const float* Wv    = (const float*)d_in[5];
  const float* bv    = (const float*)d_in[6];
  const float* gQ    = (const float*)d_in[7];
  const float* betaQ = (const float*)d_in[8];
  const float* gK    = (const float*)d_in[9];
  const float* betaK = (const float*)d_in[10];
  const float* gV    = (const float*)d_in[11];
  const float* betaV = (const float*)d_in[12];
  float* out = (float*)d_out;

  char* wsp = (char*)d_ws;
  u16*   xT    = (u16*)(wsp + OFF_XT);
  u16*   Wall  = (u16*)(wsp + OFF_WALL);
  float* ball  = (float*)(wsp + OFF_BALL);
  float* Mg    = (float*)(wsp + OFF_M);
  float* sx    = (float*)(wsp + OFF_SX);
  float* s_all = (float*)(wsp + OFF_SALL);
  float* t_all = (float*)(wsp + OFF_TALL);
  float* aL4   = (float*)(wsp + OFF_AL4);
  float* Mpart = (float*)(wsp + OFF_MPART);

  k_prep<<<NTOT, 256, 0, stream>>>(Wq, bq, Wk, bk, Wv, bv, Wall, ball, sx);
  k_M<<<256, 512, 0, stream>>>(x, xT, Mpart, sx);
  k_red<<<256, 256, 0, stream>>>(Mpart, Mg);
  k_stats2<<<NTOT, 256, 0, stream>>>(Mg, sx, Wq, bq, Wk, bk, Wv, bv,
                                     gQ, betaQ, gK, betaK, gV, betaV, s_all, t_all);
  k_qk<<<NB * NHEADS, 768, 0, stream>>>(xT, Wall, ball, s_all, t_all, aL4);
  k_v<<<NB * NHEADS, 768, 0, stream>>>(xT, Wall, ball, s_all, t_all, aL4, x, out);
}